// Round 8
// baseline (5779.006 us; speedup 1.0000x reference)
//
#include <hip/hip_runtime.h>
#include <hip/hip_bf16.h>
#include <stdint.h>

// B=64, T=512, D=128, H=512, C=256
#define SMEM_BYTES 150528

using short8  = __attribute__((ext_vector_type(8))) short;
using f32x4   = __attribute__((ext_vector_type(4))) float;
using u32x4   = __attribute__((ext_vector_type(4))) unsigned int;

// ---------------- workspace layout (bytes) ----------------
#define OXBF 0u
#define OYBF 8388608u
#define OWE0 16777216u               // cell0 enc blob: 32 ub * 81920
#define OWD0 (OWE0 + 2621440u)
#define OWE1 (OWD0 + 2621440u)       // cell1 enc blob: 32 ub * 131072
#define OWD1 (OWE1 + 4194304u)
#define OWC1 (OWD1 + 4194304u)       // 16 * 16KB
#define OWC2 (OWC1 + 262144u)        // 8 * 8KB
#define OH0  (OWC2 + 65536u)         // h0 ring [8][64][512] bf16 = 512KB
#define OH1  (OH0 + 524288u)         // h1 ring, ENCODER contents (t<512)
#define OHP  (OH1 + 524288u)         // hid ring [8][64][256] bf16 = 256KB
#define OFLG (OHP + 262144u)         // flags (progress, 64B apart)
#define OFC1 (OFLG + 4096u)          // c1 progress: 64 flags
#define OFH  (OFLG + 8192u)          // hid progress: 16 flags
#define OFL  (OFLG + 9216u)          // log progress: 8 flags
#define OH1B (OFLG + 16384u)         // h1 ring, DECODER contents (t>=512), 512KB

// ---------------- helpers ----------------
static __device__ __forceinline__ unsigned short f2bf(float f){
  union { float f; unsigned u; } v; v.f = f;
  unsigned r = v.u + 0x7FFFu + ((v.u >> 16) & 1u);
  return (unsigned short)(r >> 16);
}
static __device__ __forceinline__ float sigm(float x){ return 1.f/(1.f+__expf(-x)); }
static __device__ __forceinline__ float tanh_(float x){ return 1.f - 2.f/(__expf(2.f*x)+1.f); }

// coherence-point (MALL) access: sc0 sc1 bypasses L1/L2 — no fences needed
static __device__ __forceinline__ u32x4 ld_cg16(const void* p){
  u32x4 v;
  asm volatile("global_load_dwordx4 %0, %1, off sc0 sc1" : "=v"(v) : "v"(p) : "memory");
  return v;
}
static __device__ __forceinline__ unsigned ld_cg4(const void* p){
  unsigned v;
  asm volatile("global_load_dword %0, %1, off sc0 sc1\n\ts_waitcnt vmcnt(0)"
               : "=v"(v) : "v"(p) : "memory");
  return v;
}
// async variant: NO waitcnt — value valid only after a later drain_vm()
static __device__ __forceinline__ unsigned ld_cg4_async(const void* p){
  unsigned v;
  asm volatile("global_load_dword %0, %1, off sc0 sc1" : "=v"(v) : "v"(p) : "memory");
  return v;
}
static __device__ __forceinline__ void st_cg16(void* p, u32x4 v){
  asm volatile("global_store_dwordx4 %0, %1, off sc0 sc1" :: "v"(p), "v"(v) : "memory");
}
static __device__ __forceinline__ void st_cg4(void* p, unsigned v){
  asm volatile("global_store_dword %0, %1, off sc0 sc1" :: "v"(p), "v"(v) : "memory");
}
static __device__ __forceinline__ void drain_vm(){
  asm volatile("s_waitcnt vmcnt(0)" ::: "memory");
}
static __device__ __forceinline__ bool isS(u32x4 v){
  return (v[0]==0xFFFFFFFFu) | (v[1]==0xFFFFFFFFu) | (v[2]==0xFFFFFFFFu) | (v[3]==0xFFFFFFFFu);
}

// ---------------- prep kernels ----------------
__global__ void k_init(float* __restrict__ out, uint8_t* __restrict__ ws){
  int i = blockIdx.x*blockDim.x + threadIdx.x;
  int ns = gridDim.x*blockDim.x;
  // h0/h1(enc) rings: slots 0..6 sentinel, slot 7 zeros (= initial h(-1)=0)
  uint32_t* r0 = (uint32_t*)(ws + OH0);
  uint32_t* r1 = (uint32_t*)(ws + OH1);
  const int slotw = 65536/4;
  for (int k=i; k<8*slotw; k+=ns){
    unsigned v = (k < 7*slotw) ? 0xFFFFFFFFu : 0u;
    r0[k] = v; r1[k] = v;
  }
  // h1 decoder region: ALL sentinel (fresh ring for hid's phase)
  uint32_t* rb = (uint32_t*)(ws + OH1B);
  for (int k=i; k<8*slotw; k+=ns) rb[k] = 0xFFFFFFFFu;
  // hid ring: all sentinel
  uint32_t* rp = (uint32_t*)(ws + OHP);
  for (int k=i; k<262144/4; k+=ns) rp[k] = 0xFFFFFFFFu;
  // flags zero
  uint32_t* fl = (uint32_t*)(ws + OFLG);
  for (int k=i; k<16384/4; k+=ns) fl[k] = 0u;
  // out row 0 zeros
  for (int k=i; k<64*128; k+=ns) out[(size_t)(k>>7)*(512*128) + (k&127)] = 0.f;
}

__global__ void k_cvt(const float* __restrict__ x, const float* __restrict__ y,
                      uint8_t* __restrict__ ws){
  unsigned short* xb = (unsigned short*)(ws + OXBF);
  unsigned short* yb = (unsigned short*)(ws + OYBF);
  const int n = 64*512*128;
  int i = blockIdx.x*blockDim.x + threadIdx.x, ns = gridDim.x*blockDim.x;
  for (int k=i; k<n; k+=ns){ xb[k] = f2bf(x[k]); yb[k] = f2bf(y[k]); }
}

// gate-cell weight swizzle: frag idx = ((((ub*4 + w)*NKK + kk)*4 + g)*64 + lane)*8 + j
// mode 1 (cell0): k = kk==0 ? w*32+off : 128 + w*128 + (kk-1)*32 + off
// mode 0 (cell1): k = w*KC + kk*32 + off
__global__ void k_swzgate(const float* __restrict__ Wih, const float* __restrict__ Whh,
                          uint8_t* __restrict__ ws, size_t dstOff, int Kin, int KC, int NKK, int mode){
  unsigned short* dst = (unsigned short*)(ws + dstOff);
  const int total = 2048 * (KC*4);
  int i = blockIdx.x*blockDim.x + threadIdx.x, ns = gridDim.x*blockDim.x;
  for (int idx=i; idx<total; idx+=ns){
    int j = idx & 7;
    int lane = (idx >> 3) & 63;
    int t = idx >> 9;
    int g = t & 3; t >>= 2;
    int kk = t % NKK; t /= NKK;
    int w = t & 3; int ub = t >> 2;
    int off = ((lane>>4)<<3) + j;
    int k = mode ? (kk==0 ? w*32 + off : 128 + w*128 + (kk-1)*32 + off)
                 : (w*KC + kk*32 + off);
    int u = ub*16 + (lane&15);
    int row = g*512 + u;
    float v = (k < Kin) ? Wih[(size_t)row*Kin + k] : Whh[(size_t)row*512 + (k-Kin)];
    dst[idx] = f2bf(v);
  }
}

// clf weight swizzle: frag idx = (((wg*4 + w)*NKK + kk)*64 + lane)*8 + j ; k = w*Kw + kk*32 + off
__global__ void k_swzclf(const float* __restrict__ W, uint8_t* __restrict__ ws,
                         size_t dstOff, int nwgs, int Kw, int Ktot){
  unsigned short* dst = (unsigned short*)(ws + dstOff);
  const int NKK = Kw/32;
  const int total = nwgs*4*NKK*64*8;
  int i = blockIdx.x*blockDim.x + threadIdx.x, ns = gridDim.x*blockDim.x;
  for (int idx=i; idx<total; idx+=ns){
    int j = idx & 7;
    int lane = (idx >> 3) & 63;
    int t = idx >> 9;
    int kk = t % NKK; t /= NKK;
    int w = t & 3; int wg = t >> 2;
    int k = w*Kw + kk*32 + ((lane>>4)<<3) + j;
    int col = wg*16 + (lane&15);
    dst[idx] = f2bf(W[(size_t)col*Ktot + k]);
  }
}

// ---------------- persistent dataflow kernel ----------------
// roles: wg 0..63 cell0 (bt=wg>>5, ub=wg&31); 64..127 cell1; 128..143 hid; 144..151 log
__launch_bounds__(256, 1)
__global__ void k_seq(uint8_t* __restrict__ ws,
                      const float* __restrict__ eb0, const float* __restrict__ eb1,
                      const float* __restrict__ db0, const float* __restrict__ db1,
                      const float* __restrict__ cb1, const float* __restrict__ cb2,
                      float* __restrict__ out){
  __shared__ uint8_t smem[SMEM_BYTES];
  const int wg = blockIdx.x, tid = threadIdx.x;
  const int w = tid>>6, l = tid&63, lr = l&15, lg = l>>4;

  const unsigned short* xb = (const unsigned short*)(ws+OXBF);
  const unsigned short* yb = (const unsigned short*)(ws+OYBF);
  unsigned short* h0r = (unsigned short*)(ws+OH0);
  unsigned short* h1r = (unsigned short*)(ws+OH1);    // h1 contents t<512
  unsigned short* h1b = (unsigned short*)(ws+OH1B);   // h1 contents t>=512
  unsigned short* hpr = (unsigned short*)(ws+OHP);

  short8* BL = (short8*)smem;
  float*  P0 = (float*)(smem + 131072);           // cell 32*68, clf 64*20 fp32
  float*  P1 = (float*)(smem + 139776);
  unsigned short* HS = (unsigned short*)(smem + 148480);  // h staging (<=2KB)

  const u32x4 S4 = (u32x4){0xFFFFFFFFu,0xFFFFFFFFu,0xFFFFFFFFu,0xFFFFFFFFu};

  auto loadB = [&](size_t srcOff, int bytes){
    const u32x4* s = (const u32x4*)(ws + srcOff);
    u32x4* d = (u32x4*)smem;
    for (int i = tid; i < bytes/16; i += 256) d[i] = s[i];
  };

  if (wg < 128){
    // ---------------- LSTM cells ----------------
    const bool isC0 = wg < 64;
    const int cwg = isC0 ? wg : wg-64;
    const int bt = cwg>>5, ub = cwg&31;
    const int u = tid&15, ug = ub*16 + u;
    const int bbytes = isC0 ? 81920 : 131072;

    float be[4], bd[4];
    {
      const float* e = isC0 ? eb0 : eb1;
      const float* d = isC0 ? db0 : db1;
      #pragma unroll
      for (int g=0; g<4; ++g){ be[g] = e[g*512+ug]; bd[g] = d[g*512+ug]; }
    }
    loadB((isC0 ? (size_t)OWE0 : (size_t)OWE1) + (size_t)ub*bbytes, bbytes);
    float cS0 = 0.f, cS1 = 0.f;
    __syncthreads();

    for (int t = 0; t < 1023; ++t){
      if (t == 512){
        __syncthreads();
        loadB((isC0 ? (size_t)OWD0 : (size_t)OWD1) + (size_t)ub*bbytes, bbytes);
        __syncthreads();
      }

      const int slotW = t&7, slotR = (t+7)&7, slotC = (t+3)&7;
      unsigned short* pub_base = isC0 ? h0r : ((t >= 512) ? h1b : h1r);

      // ---- async WAR-flag prefetch (wave0; retired by detect drains) ----
      const bool gateAct = isC0 ? (t >= 4) : (t >= 517);
      const int  ng      = isC0 ? 32 : 16;
      const void* fp = isC0 ? (const void*)(ws + OFC1 + (size_t)(bt*32 + (l&31))*64)
                            : (const void*)(ws + OFH  + (size_t)(l&15)*64);
      unsigned fv = 0u;
      if (w == 0 && l < ng && gateAct) fv = ld_cg4_async(fp);

      f32x4 acc[2][4];
      #pragma unroll
      for (int m=0;m<2;++m)
        #pragma unroll
        for (int g=0;g<4;++g) acc[m][g] = (f32x4){0.f,0.f,0.f,0.f};

      if (isC0){
        const unsigned short* xs = (t<512) ? xb : yb;
        const int tt = (t<512) ? t : t-512;
        short8 ax[2];
        #pragma unroll
        for (int m=0;m<2;++m){
          const int b = bt*32 + m*16 + lr;
          ax[m] = *(const short8*)(xs + ((size_t)b*512 + tt)*128 + w*32 + (lg<<3));
        }
        // data-sentinel poll on h0(t-1), 8 chunks
        u32x4 ah[4][2];
        const unsigned short* base = h0r + (size_t)slotR*64*512;
        bool bad;
        do {
          #pragma unroll
          for (int kk=0; kk<4; ++kk)
            #pragma unroll
            for (int m=0;m<2;++m){
              const int b = bt*32 + m*16 + lr;
              ah[kk][m] = ld_cg16(base + (size_t)b*512 + w*128 + kk*32 + (lg<<3));
            }
          drain_vm();
          __builtin_amdgcn_sched_barrier(0);   // pin sentinel check AFTER the waitcnt (rule #18)
          bad = false;
          #pragma unroll
          for (int kk=0; kk<4; ++kk)
            #pragma unroll
            for (int m=0;m<2;++m) bad |= isS(ah[kk][m]);
          if (bad) __builtin_amdgcn_s_sleep(1);
        } while (bad);
        __builtin_amdgcn_sched_barrier(0);
        #pragma unroll
        for (int g=0;g<4;++g){
          short8 bf = BL[((w*5+0)*4+g)*64 + l];
          acc[0][g] = __builtin_amdgcn_mfma_f32_16x16x32_bf16(ax[0], bf, acc[0][g],0,0,0);
          acc[1][g] = __builtin_amdgcn_mfma_f32_16x16x32_bf16(ax[1], bf, acc[1][g],0,0,0);
        }
        #pragma unroll
        for (int kk=1; kk<5; ++kk)
          #pragma unroll
          for (int g=0;g<4;++g){
            short8 bf = BL[((w*5+kk)*4+g)*64 + l];
            acc[0][g] = __builtin_amdgcn_mfma_f32_16x16x32_bf16(__builtin_bit_cast(short8, ah[kk-1][0]), bf, acc[0][g],0,0,0);
            acc[1][g] = __builtin_amdgcn_mfma_f32_16x16x32_bf16(__builtin_bit_cast(short8, ah[kk-1][1]), bf, acc[1][g],0,0,0);
          }
      } else {
        // data-sentinel poll on h0(t) + h1(t-1), 16 chunks
        u32x4 a[8][2];
        const unsigned short* b0 = h0r + (size_t)slotW*64*512;
        const unsigned short* b1 = ((t-1 >= 512) ? h1b : h1r) + (size_t)slotR*64*512;
        bool bad;
        do {
          #pragma unroll
          for (int kk=0; kk<8; ++kk){
            const int k0 = w*256 + kk*32;
            #pragma unroll
            for (int m=0;m<2;++m){
              const int b = bt*32 + m*16 + lr;
              const void* ap = (k0 < 512)
                ? (const void*)(b0 + (size_t)b*512 + k0 + (lg<<3))
                : (const void*)(b1 + (size_t)b*512 + (k0-512) + (lg<<3));
              a[kk][m] = ld_cg16(ap);
            }
          }
          drain_vm();
          __builtin_amdgcn_sched_barrier(0);   // pin sentinel check AFTER the waitcnt (rule #18)
          bad = false;
          #pragma unroll
          for (int kk=0; kk<8; ++kk)
            #pragma unroll
            for (int m=0;m<2;++m) bad |= isS(a[kk][m]);
          if (bad) __builtin_amdgcn_s_sleep(1);
        } while (bad);
        __builtin_amdgcn_sched_barrier(0);
        #pragma unroll
        for (int kk=0; kk<8; ++kk)
          #pragma unroll
          for (int g=0;g<4;++g){
            short8 bf = BL[((w*8+kk)*4+g)*64 + l];
            acc[0][g] = __builtin_amdgcn_mfma_f32_16x16x32_bf16(__builtin_bit_cast(short8, a[kk][0]), bf, acc[0][g],0,0,0);
            acc[1][g] = __builtin_amdgcn_mfma_f32_16x16x32_bf16(__builtin_bit_cast(short8, a[kk][1]), bf, acc[1][g],0,0,0);
          }
      }

      // 2-round split-K reduce: w0->P0, w1->P1; barrier; w2->P0+, w3->P1+
      {
        float* P = (w&1) ? P1 : P0;
        if (w < 2){
          #pragma unroll
          for (int m=0;m<2;++m)
            #pragma unroll
            for (int g=0;g<4;++g)
              #pragma unroll
              for (int r=0;r<4;++r)
                P[(m*16 + (lg<<2) + r)*68 + g*16 + lr] = acc[m][g][r];
        }
        __syncthreads();
        if (w >= 2){
          #pragma unroll
          for (int m=0;m<2;++m)
            #pragma unroll
            for (int g=0;g<4;++g)
              #pragma unroll
              for (int r=0;r<4;++r)
                P[(m*16 + (lg<<2) + r)*68 + g*16 + lr] += acc[m][g][r];
        }
        __syncthreads();
      }

      // ---- WAR check (prefetched flag, free drain) + sentinel-clear slot t+3 ----
      if (w == 0){
        drain_vm();                          // nothing outstanding: free; makes fv readable
        __builtin_amdgcn_sched_barrier(0);   // pin check after waitcnt (rule #18)
        if (gateAct && l < ng){
          const int n0 = isC0 ? (t-4) : (t-516);
          const int need = (n0 < 1) ? 1 : n0;
          int v = (int)fv;
          while (v < need){ v = (int)ld_cg4(fp); __builtin_amdgcn_s_sleep(2); }
        }
        if (t >= 4 && t <= 1019){
          unsigned short* cbase = isC0 ? h0r : ((t+3 >= 512) ? h1b : h1r);
          const int row = l>>1, half = l&1;
          st_cg16(cbase + ((size_t)slotC*64 + bt*32 + row)*512 + ub*16 + half*8, S4);
        }
      }

      // activation epilogue -> LDS staging
      const float* bias = (t<512) ? be : bd;
      #pragma unroll
      for (int s=0;s<2;++s){
        const int row = (tid>>4) + s*16;
        const int pi = row*68 + u;
        float gi = P0[pi]      + P1[pi]      + bias[0];
        float gf = P0[pi+16]   + P1[pi+16]   + bias[1];
        float gg = P0[pi+32]   + P1[pi+32]   + bias[2];
        float go = P0[pi+48]   + P1[pi+48]   + bias[3];
        float cprev = s ? cS1 : cS0;
        float c = sigm(gf)*cprev + sigm(gi)*tanh_(gg);
        if (s) cS1 = c; else cS0 = c;
        float h = sigm(go)*tanh_(c);
        HS[row*16 + u] = f2bf(h);
      }
      __syncthreads();
      // publish: 64 x 16B vector stores by wave 0 (acks retire under next detect)
      if (tid < 64){
        u32x4 v = *(const u32x4*)(HS + tid*8);
        const int row = tid>>1, half = tid&1;
        st_cg16(pub_base + ((size_t)slotW*64 + bt*32 + row)*512 + ub*16 + half*8, v);
      }
      if (!isC0 && tid == 0)
        st_cg4(ws + OFC1 + (size_t)(bt*32+ub)*64, (unsigned)(t+1));
    }
  } else if (wg < 144){
    // ---------------- clf hidden: relu(h1 @ W1^T + b1) ----------------
    const int hwg = wg - 128;
    const int u = tid&15, col = hwg*16 + u;
    const float bc = cb1[col];
    loadB((size_t)OWC1 + (size_t)hwg*16384, 16384);
    __syncthreads();
    for (int t2 = 0; t2 < 511; ++t2){
      const int slot = t2&7, slotC = (t2+3)&7;
      const bool gateAct = (t2 >= 5);
      const void* fp = (const void*)(ws + OFL + (size_t)(l&7)*64);
      unsigned fv = 0u;
      if (w == 0 && l < 8 && gateAct) fv = ld_cg4_async(fp);

      u32x4 a[4][4];
      const unsigned short* base = h1b + (size_t)slot*64*512;   // decoder region only
      bool bad;
      do {
        #pragma unroll
        for (int kk=0; kk<4; ++kk)
          #pragma unroll
          for (int m=0;m<4;++m)
            a[kk][m] = ld_cg16(base + (size_t)(m*16+lr)*512 + w*128 + kk*32 + (lg<<3));
        drain_vm();
        __builtin_amdgcn_sched_barrier(0);   // pin sentinel check AFTER the waitcnt (rule #18)
        bad = false;
        #pragma unroll
        for (int kk=0; kk<4; ++kk)
          #pragma unroll
          for (int m=0;m<4;++m) bad |= isS(a[kk][m]);
        if (bad) __builtin_amdgcn_s_sleep(1);
      } while (bad);
      __builtin_amdgcn_sched_barrier(0);
      f32x4 ha[4];
      #pragma unroll
      for (int m=0;m<4;++m) ha[m] = (f32x4){0.f,0.f,0.f,0.f};
      #pragma unroll
      for (int kk=0; kk<4; ++kk){
        short8 bf = BL[(w*4+kk)*64 + l];
        #pragma unroll
        for (int m=0;m<4;++m)
          ha[m] = __builtin_amdgcn_mfma_f32_16x16x32_bf16(__builtin_bit_cast(short8, a[kk][m]), bf, ha[m],0,0,0);
      }
      {
        float* P = (w&1) ? P1 : P0;
        if (w < 2){
          #pragma unroll
          for (int m=0;m<4;++m)
            #pragma unroll
            for (int r=0;r<4;++r)
              P[(m*16 + (lg<<2) + r)*20 + lr] = ha[m][r];
        }
        __syncthreads();
        if (w >= 2){
          #pragma unroll
          for (int m=0;m<4;++m)
            #pragma unroll
            for (int r=0;r<4;++r)
              P[(m*16 + (lg<<2) + r)*20 + lr] += ha[m][r];
        }
        __syncthreads();
      }
      // ---- WAR check + clears (post-reduce) ----
      if (w == 0){
        drain_vm();
        __builtin_amdgcn_sched_barrier(0);
        if (gateAct && l < 8){
          const int n0 = t2 - 4;
          const int need = (n0 < 1) ? 1 : n0;
          int v = (int)fv;
          while (v < need){ v = (int)ld_cg4(fp); __builtin_amdgcn_s_sleep(2); }
        }
        if (t2 >= 5 && t2 <= 507){
          #pragma unroll
          for (int q=0;q<2;++q)
            st_cg16(hpr + ((size_t)slotC*64 + l)*256 + hwg*16 + q*8, S4);
        }
      }
      #pragma unroll
      for (int s=0;s<4;++s){
        const int row = (tid>>4) + s*16;
        float v = P0[row*20+u] + P1[row*20+u] + bc;
        HS[row*16 + u] = f2bf(fmaxf(v, 0.f));
      }
      __syncthreads();
      if (tid < 128){
        u32x4 v = *(const u32x4*)(HS + tid*8);
        const int row = tid>>1, half = tid&1;
        st_cg16(hpr + ((size_t)slot*64 + row)*256 + hwg*16 + half*8, v);
      }
      if (tid == 0) st_cg4(ws + OFH + (size_t)hwg*64, (unsigned)(t2+1));
    }
  } else if (wg < 152){
    // ---------------- clf logits: hid @ W2^T + b2 -> out ----------------
    const int lwg = wg - 144;
    const int u = tid&15, col = lwg*16 + u;
    const float bc = cb2[col];
    loadB((size_t)OWC2 + (size_t)lwg*8192, 8192);
    __syncthreads();
    for (int t3 = 0; t3 < 511; ++t3){
      const int slot = t3&7;
      u32x4 a[2][4];
      const unsigned short* base = hpr + (size_t)slot*64*256;
      bool bad;
      do {
        #pragma unroll
        for (int kk=0; kk<2; ++kk)
          #pragma unroll
          for (int m=0;m<4;++m)
            a[kk][m] = ld_cg16(base + (size_t)(m*16+lr)*256 + w*64 + kk*32 + (lg<<3));
        drain_vm();
        __builtin_amdgcn_sched_barrier(0);   // pin sentinel check AFTER the waitcnt (rule #18)
        bad = false;
        #pragma unroll
        for (int kk=0; kk<2; ++kk)
          #pragma unroll
          for (int m=0;m<4;++m) bad |= isS(a[kk][m]);
        if (bad) __builtin_amdgcn_s_sleep(1);
      } while (bad);
      __builtin_amdgcn_sched_barrier(0);
      f32x4 la[4];
      #pragma unroll
      for (int m=0;m<4;++m) la[m] = (f32x4){0.f,0.f,0.f,0.f};
      #pragma unroll
      for (int kk=0; kk<2; ++kk){
        short8 bf = BL[(w*2+kk)*64 + l];
        #pragma unroll
        for (int m=0;m<4;++m)
          la[m] = __builtin_amdgcn_mfma_f32_16x16x32_bf16(__builtin_bit_cast(short8, a[kk][m]), bf, la[m],0,0,0);
      }
      {
        float* P = (w&1) ? P1 : P0;
        if (w < 2){
          #pragma unroll
          for (int m=0;m<4;++m)
            #pragma unroll
            for (int r=0;r<4;++r)
              P[(m*16 + (lg<<2) + r)*20 + lr] = la[m][r];
        }
        __syncthreads();
        if (w >= 2){
          #pragma unroll
          for (int m=0;m<4;++m)
            #pragma unroll
            for (int r=0;r<4;++r)
              P[(m*16 + (lg<<2) + r)*20 + lr] += la[m][r];
        }
        __syncthreads();
      }
      #pragma unroll
      for (int s=0;s<4;++s){
        const int row = (tid>>4) + s*16;
        float v = P0[row*20+u] + P1[row*20+u] + bc;
        out[((size_t)row*512 + (t3+1))*128 + col] = v;
      }
      if (tid == 0) st_cg4(ws + OFL + (size_t)lwg*64, (unsigned)(t3+1));
    }
  }
}

// ---------------- launch ----------------
extern "C" void kernel_launch(void* const* d_in, const int* in_sizes, int n_in,
                              void* d_out, int out_size, void* d_ws, size_t ws_size,
                              hipStream_t stream){
  const float* x   = (const float*)d_in[0];
  const float* y   = (const float*)d_in[1];
  const float* eW0 = (const float*)d_in[2];
  const float* eU0 = (const float*)d_in[3];
  const float* eb0 = (const float*)d_in[4];
  const float* eW1 = (const float*)d_in[5];
  const float* eU1 = (const float*)d_in[6];
  const float* eb1 = (const float*)d_in[7];
  const float* dW0 = (const float*)d_in[8];
  const float* dU0 = (const float*)d_in[9];
  const float* db0 = (const float*)d_in[10];
  const float* dW1 = (const float*)d_in[11];
  const float* dU1 = (const float*)d_in[12];
  const float* db1 = (const float*)d_in[13];
  const float* cW1 = (const float*)d_in[14];
  const float* cb1 = (const float*)d_in[15];
  const float* cW2 = (const float*)d_in[16];
  const float* cb2 = (const float*)d_in[17];
  float* out = (float*)d_out;
  uint8_t* ws = (uint8_t*)d_ws;
  (void)in_sizes; (void)n_in; (void)out_size; (void)ws_size;

  k_init<<<dim3(256), dim3(256), 0, stream>>>(out, ws);
  k_cvt<<<dim3(2048), dim3(256), 0, stream>>>(x, y, ws);
  k_swzgate<<<dim3(1280), dim3(256), 0, stream>>>(eW0, eU0, ws, (size_t)OWE0, 128, 160, 5, 1);
  k_swzgate<<<dim3(1280), dim3(256), 0, stream>>>(dW0, dU0, ws, (size_t)OWD0, 128, 160, 5, 1);
  k_swzgate<<<dim3(2048), dim3(256), 0, stream>>>(eW1, eU1, ws, (size_t)OWE1, 512, 256, 8, 0);
  k_swzgate<<<dim3(2048), dim3(256), 0, stream>>>(dW1, dU1, ws, (size_t)OWD1, 512, 256, 8, 0);
  k_swzclf<<<dim3(256), dim3(256), 0, stream>>>(cW1, ws, (size_t)OWC1, 16, 128, 512);
  k_swzclf<<<dim3(64),  dim3(256), 0, stream>>>(cW2, ws, (size_t)OWC2, 8, 64, 256);
  k_seq<<<dim3(152), dim3(256), 0, stream>>>(ws, eb0, eb1, db0, db1, cb1, cb2, out);
}

// Round 10
// 5280.840 us; speedup vs baseline: 1.0943x; 1.0943x over previous
//
#include <hip/hip_runtime.h>
#include <hip/hip_bf16.h>
#include <stdint.h>

// B=64, T=512, D=128, H=512, C=256
#define SMEM_BYTES 150528

using short8  = __attribute__((ext_vector_type(8))) short;
using f32x4   = __attribute__((ext_vector_type(4))) float;
using u32x4   = __attribute__((ext_vector_type(4))) unsigned int;

// ---------------- workspace layout (bytes) ----------------
#define OXBF 0u
#define OYBF 8388608u
#define OWE0 16777216u               // cell0 enc blob: 32 ub * 81920
#define OWD0 (OWE0 + 2621440u)
#define OWE1 (OWD0 + 2621440u)       // cell1 enc blob: 32 ub * 131072
#define OWD1 (OWE1 + 4194304u)
#define OWC1 (OWD1 + 4194304u)       // 16 * 16KB
#define OWC2 (OWC1 + 262144u)        // 8 * 8KB
#define OA0  (OWC2 + 65536u)         // h0 intra ring (group-L2 when loc) [8][64][512]
#define OB0  (OA0 + 524288u)         // h0 cross/fallback ring (MALL)
#define OA1  (OB0 + 524288u)         // h1 intra ring
#define OB1  (OA1 + 524288u)         // h1 cross ring (decoder contents, MALL)
#define OHP  (OB1 + 524288u)         // hid ring [8][64][256]
#define OFLG (OHP + 262144u)         // flags (64B apart)
#define OFC1 (OFLG + 4096u)          // c1 progress: 64 flags (MALL)
#define OFH  (OFLG + 8192u)          // hid progress: 16 flags (MALL)
#define OFL  (OFLG + 9216u)          // log progress: 8 flags (clf-group scope)
#define OPRB (OFLG + 16384u)         // probe tokens: 256 * 64B (sc0 world)
#define OVOT (OFLG + 32768u)         // probe votes:  256 * 64B (MALL world)

#define GUARD (1<<19)

// ---------------- helpers ----------------
static __device__ __forceinline__ unsigned short f2bf(float f){
  union { float f; unsigned u; } v; v.f = f;
  unsigned r = v.u + 0x7FFFu + ((v.u >> 16) & 1u);
  return (unsigned short)(r >> 16);
}
static __device__ __forceinline__ float sigm(float x){ return 1.f/(1.f+__expf(-x)); }
static __device__ __forceinline__ float tanh_(float x){ return 1.f - 2.f/(__expf(2.f*x)+1.f); }

// scoped access: loc=true -> sc0 (L2, same-XCD only); loc=false -> sc0 sc1 (MALL)
static __device__ __forceinline__ u32x4 ld_r16(const void* p, bool loc){
  u32x4 v;
  if (loc) asm volatile("global_load_dwordx4 %0, %1, off sc0"     : "=v"(v) : "v"(p) : "memory");
  else     asm volatile("global_load_dwordx4 %0, %1, off sc0 sc1" : "=v"(v) : "v"(p) : "memory");
  return v;
}
static __device__ __forceinline__ void st_r16(void* p, u32x4 v, bool loc){
  if (loc) asm volatile("global_store_dwordx4 %0, %1, off sc0"     :: "v"(p), "v"(v) : "memory");
  else     asm volatile("global_store_dwordx4 %0, %1, off sc0 sc1" :: "v"(p), "v"(v) : "memory");
}
static __device__ __forceinline__ unsigned ld_f4(const void* p, bool loc){
  unsigned v;
  if (loc) asm volatile("global_load_dword %0, %1, off sc0\n\ts_waitcnt vmcnt(0)"     : "=v"(v) : "v"(p) : "memory");
  else     asm volatile("global_load_dword %0, %1, off sc0 sc1\n\ts_waitcnt vmcnt(0)" : "=v"(v) : "v"(p) : "memory");
  return v;
}
static __device__ __forceinline__ unsigned ld_f4a(const void* p, bool loc){  // async
  unsigned v;
  if (loc) asm volatile("global_load_dword %0, %1, off sc0"     : "=v"(v) : "v"(p) : "memory");
  else     asm volatile("global_load_dword %0, %1, off sc0 sc1" : "=v"(v) : "v"(p) : "memory");
  return v;
}
static __device__ __forceinline__ void st_f4(void* p, unsigned v, bool loc){
  if (loc) asm volatile("global_store_dword %0, %1, off sc0"     :: "v"(p), "v"(v) : "memory");
  else     asm volatile("global_store_dword %0, %1, off sc0 sc1" :: "v"(p), "v"(v) : "memory");
}
static __device__ __forceinline__ void drain_vm(){
  asm volatile("s_waitcnt vmcnt(0)" ::: "memory");
}
static __device__ __forceinline__ bool isS(u32x4 v){
  return (v[0]==0xFFFFFFFFu) | (v[1]==0xFFFFFFFFu) | (v[2]==0xFFFFFFFFu) | (v[3]==0xFFFFFFFFu);
}

// ---------------- prep kernels ----------------
__global__ void k_init(float* __restrict__ out, uint8_t* __restrict__ ws){
  int i = blockIdx.x*blockDim.x + threadIdx.x;
  int ns = gridDim.x*blockDim.x;
  uint32_t* r = (uint32_t*)(ws + OA0);
  const int nring = (4*524288 + 262144)/4;
  for (int k=i; k<nring; k+=ns) r[k] = 0xFFFFFFFFu;
  uint32_t* fl = (uint32_t*)(ws + OFLG);
  for (int k=i; k<49152/4; k+=ns) fl[k] = 0u;   // flags + probe + votes
  for (int k=i; k<64*128; k+=ns) out[(size_t)(k>>7)*(512*128) + (k&127)] = 0.f;
}

__global__ void k_cvt(const float* __restrict__ x, const float* __restrict__ y,
                      uint8_t* __restrict__ ws){
  unsigned short* xb = (unsigned short*)(ws + OXBF);
  unsigned short* yb = (unsigned short*)(ws + OYBF);
  const int n = 64*512*128;
  int i = blockIdx.x*blockDim.x + threadIdx.x, ns = gridDim.x*blockDim.x;
  for (int k=i; k<n; k+=ns){ xb[k] = f2bf(x[k]); yb[k] = f2bf(y[k]); }
}

__global__ void k_swzgate(const float* __restrict__ Wih, const float* __restrict__ Whh,
                          uint8_t* __restrict__ ws, size_t dstOff, int Kin, int KC, int NKK, int mode){
  unsigned short* dst = (unsigned short*)(ws + dstOff);
  const int total = 2048 * (KC*4);
  int i = blockIdx.x*blockDim.x + threadIdx.x, ns = gridDim.x*blockDim.x;
  for (int idx=i; idx<total; idx+=ns){
    int j = idx & 7;
    int lane = (idx >> 3) & 63;
    int t = idx >> 9;
    int g = t & 3; t >>= 2;
    int kk = t % NKK; t /= NKK;
    int w = t & 3; int ub = t >> 2;
    int off = ((lane>>4)<<3) + j;
    int k = mode ? (kk==0 ? w*32 + off : 128 + w*128 + (kk-1)*32 + off)
                 : (w*KC + kk*32 + off);
    int u = ub*16 + (lane&15);
    int row = g*512 + u;
    float v = (k < Kin) ? Wih[(size_t)row*Kin + k] : Whh[(size_t)row*512 + (k-Kin)];
    dst[idx] = f2bf(v);
  }
}

__global__ void k_swzclf(const float* __restrict__ W, uint8_t* __restrict__ ws,
                         size_t dstOff, int nwgs, int Kw, int Ktot){
  unsigned short* dst = (unsigned short*)(ws + dstOff);
  const int NKK = Kw/32;
  const int total = nwgs*4*NKK*64*8;
  int i = blockIdx.x*blockDim.x + threadIdx.x, ns = gridDim.x*blockDim.x;
  for (int idx=i; idx<total; idx+=ns){
    int j = idx & 7;
    int lane = (idx >> 3) & 63;
    int t = idx >> 9;
    int kk = t % NKK; t /= NKK;
    int w = t & 3; int wg = t >> 2;
    int k = w*Kw + kk*32 + ((lane>>4)<<3) + j;
    int col = wg*16 + (lane&15);
    dst[idx] = f2bf(W[(size_t)col*Ktot + k]);
  }
}

// ---------------- persistent dataflow kernel ----------------
// grid 256; xcd = wg&7, j = wg>>3:
//   xcd 0/1: cell0 bt=xcd (ub=j) | xcd 2/3: cell1 bt=xcd-2 | xcd 4: j<16 hid, j<24 log | else idle
__launch_bounds__(256, 1)
__global__ void k_seq(uint8_t* __restrict__ ws,
                      const float* __restrict__ eb0, const float* __restrict__ eb1,
                      const float* __restrict__ db0, const float* __restrict__ db1,
                      const float* __restrict__ cb1, const float* __restrict__ cb2,
                      float* __restrict__ out){
  __shared__ uint8_t smem[SMEM_BYTES];
  const int wg = blockIdx.x, tid = threadIdx.x;
  const int w = tid>>6, l = tid&63, lr = l&15, lg = l>>4;
  const int xcd = wg & 7, j = wg >> 3;

  int role; // 0=c0, 1=c1, 2=hid, 3=log
  if (xcd < 2) role = 0;
  else if (xcd < 4) role = 1;
  else if (xcd == 4 && j < 16) role = 2;
  else if (xcd == 4 && j < 24) role = 3;
  else return;

  const unsigned short* xb = (const unsigned short*)(ws+OXBF);
  const unsigned short* yb = (const unsigned short*)(ws+OYBF);
  unsigned short* A0e = (unsigned short*)(ws+OA0);
  unsigned short* B0e = (unsigned short*)(ws+OB0);
  unsigned short* A1e = (unsigned short*)(ws+OA1);
  unsigned short* B1e = (unsigned short*)(ws+OB1);
  unsigned short* hpr = (unsigned short*)(ws+OHP);

  short8* BL = (short8*)smem;
  float*  P0 = (float*)(smem + 131072);
  float*  P1 = (float*)(smem + 139776);
  unsigned short* HS = (unsigned short*)(smem + 148480);

  const u32x4 S4 = (u32x4){0xFFFFFFFFu,0xFFFFFFFFu,0xFFFFFFFFu,0xFFFFFFFFu};
  const u32x4 Z4 = (u32x4){0u,0u,0u,0u};

  // ---- empirical coherence probe: 3-gen bounded ping-pong over sc0 + MALL vote ----
  bool loc;
  {
    const int n   = (role <= 1) ? 32 : 24;
    const int bas = (role <= 1) ? xcd : 4;
    if (w == 0){
      bool ok = true;
      #pragma unroll 1
      for (int gen = 1; gen <= 3; ++gen){
        if (l == 0) st_f4(ws + OPRB + (size_t)wg*64u, (unsigned)gen, true);
        if (l < n){
          const void* p = ws + OPRB + (size_t)(bas + 8*l)*64u;
          int spins = 0; unsigned e;
          do { e = ld_f4(p, true); } while ((int)e < gen && ++spins < 1024);
          if ((int)e < gen) ok = false;
        }
      }
      unsigned long long b1 = __ballot(ok);
      bool wgok = (b1 == ~0ULL);
      if (l == 0) st_f4(ws + OVOT + (size_t)wg*64u, wgok ? 2u : 1u, false);
      bool vok = wgok;
      if (l < n){
        const void* p = ws + OVOT + (size_t)(bas + 8*l)*64u;
        unsigned v;
        do { v = ld_f4(p, false); } while (v == 0u);   // votes always arrive (probe bounded)
        vok = vok && (v == 2u);
      }
      unsigned long long b2 = __ballot(vok);
      if (l == 0) *(int*)HS = (b2 == ~0ULL) ? 1 : 0;
    }
    __syncthreads();
    loc = (*(volatile int*)HS) != 0;
    __syncthreads();
  }

  auto loadB = [&](size_t srcOff, int bytes){
    const u32x4* s = (const u32x4*)(ws + srcOff);
    u32x4* d = (u32x4*)smem;
    for (int i = tid; i < bytes/16; i += 256) d[i] = s[i];
  };

  if (role <= 1){
    // ---------------- LSTM cells ----------------
    const bool isC0 = (role == 0);
    const int bt = isC0 ? xcd : xcd-2, ub = j;
    const int u = tid&15, ug = ub*16 + u;
    const int bbytes = isC0 ? 81920 : 131072;
    unsigned short* OWN0 = loc ? A0e : B0e;   // c0 own ring (scope loc)

    float be[4], bd[4];
    {
      const float* e = isC0 ? eb0 : eb1;
      const float* d = isC0 ? db0 : db1;
      #pragma unroll
      for (int g=0; g<4; ++g){ be[g] = e[g*512+ug]; bd[g] = d[g*512+ug]; }
    }
    loadB((isC0 ? (size_t)OWE0 : (size_t)OWE1) + (size_t)ub*bbytes, bbytes);
    float cS0 = 0.f, cS1 = 0.f;
    __syncthreads();

    for (int t = 0; t < 1023; ++t){
      if (t == 512){
        __syncthreads();
        loadB((isC0 ? (size_t)OWD0 : (size_t)OWD1) + (size_t)ub*bbytes, bbytes);
        __syncthreads();
      }

      const int slotW = t&7, slotR = (t+7)&7, slotC = (t+3)&7;

      // cross-WAR flag prefetch (async; retired by detect drains)
      const bool gateAct = isC0 ? (t >= 4) : (t >= 517);
      const int  ng      = isC0 ? 32 : 16;
      const void* fp = isC0 ? (const void*)(ws + OFC1 + (size_t)(bt*32 + (l&31))*64)
                            : (const void*)(ws + OFH  + (size_t)(l&15)*64);
      unsigned fv = 0u;
      if (w == 0 && l < ng && gateAct) fv = ld_f4a(fp, false);

      f32x4 acc[2][4];
      #pragma unroll
      for (int m=0;m<2;++m)
        #pragma unroll
        for (int g=0;g<4;++g) acc[m][g] = (f32x4){0.f,0.f,0.f,0.f};

      if (isC0){
        const unsigned short* xs = (t<512) ? xb : yb;
        const int tt = (t<512) ? t : t-512;
        short8 ax[2];
        #pragma unroll
        for (int m=0;m<2;++m){
          const int b = bt*32 + m*16 + lr;
          ax[m] = *(const short8*)(xs + ((size_t)b*512 + tt)*128 + w*32 + (lg<<3));
        }
        u32x4 ah[4][2];
        if (t > 0){
          const unsigned short* base = OWN0 + (size_t)slotR*64*512;
          int gd = 0; bool bad;
          do {
            #pragma unroll
            for (int kk=0; kk<4; ++kk)
              #pragma unroll
              for (int m=0;m<2;++m){
                const int b = bt*32 + m*16 + lr;
                ah[kk][m] = ld_r16(base + (size_t)b*512 + w*128 + kk*32 + (lg<<3), loc);
              }
            drain_vm();
            __builtin_amdgcn_sched_barrier(0);   // rule #18
            bad = false;
            #pragma unroll
            for (int kk=0; kk<4; ++kk)
              #pragma unroll
              for (int m=0;m<2;++m) bad |= isS(ah[kk][m]);
            if (bad) __builtin_amdgcn_s_sleep(1);
          } while (bad && ++gd < GUARD);
          __builtin_amdgcn_sched_barrier(0);
        } else {
          #pragma unroll
          for (int kk=0; kk<4; ++kk)
            #pragma unroll
            for (int m=0;m<2;++m) ah[kk][m] = Z4;
        }
        #pragma unroll
        for (int g=0;g<4;++g){
          short8 bf = BL[((w*5+0)*4+g)*64 + l];
          acc[0][g] = __builtin_amdgcn_mfma_f32_16x16x32_bf16(ax[0], bf, acc[0][g],0,0,0);
          acc[1][g] = __builtin_amdgcn_mfma_f32_16x16x32_bf16(ax[1], bf, acc[1][g],0,0,0);
        }
        #pragma unroll
        for (int kk=1; kk<5; ++kk)
          #pragma unroll
          for (int g=0;g<4;++g){
            short8 bf = BL[((w*5+kk)*4+g)*64 + l];
            acc[0][g] = __builtin_amdgcn_mfma_f32_16x16x32_bf16(__builtin_bit_cast(short8, ah[kk-1][0]), bf, acc[0][g],0,0,0);
            acc[1][g] = __builtin_amdgcn_mfma_f32_16x16x32_bf16(__builtin_bit_cast(short8, ah[kk-1][1]), bf, acc[1][g],0,0,0);
          }
      } else {
        // waves 0-1: h0(t) from B0 (MALL); waves 2-3: h1(t-1) from own ring
        u32x4 a[8][2];
        const bool wv01 = (w < 2);
        if (wv01 || t > 0){
          const unsigned short* base;
          bool myloc;
          if (wv01){ base = B0e + (size_t)slotW*64*512; myloc = false; }
          else {
            base = (loc ? A1e : (((t-1) >= 512) ? B1e : A1e)) + (size_t)slotR*64*512;
            myloc = loc;
          }
          const int kbase = wv01 ? (w*256) : (w*256 - 512);
          int gd = 0; bool bad;
          do {
            #pragma unroll
            for (int kk=0; kk<8; ++kk)
              #pragma unroll
              for (int m=0;m<2;++m){
                const int b = bt*32 + m*16 + lr;
                a[kk][m] = ld_r16(base + (size_t)b*512 + kbase + kk*32 + (lg<<3), myloc);
              }
            drain_vm();
            __builtin_amdgcn_sched_barrier(0);   // rule #18
            bad = false;
            #pragma unroll
            for (int kk=0; kk<8; ++kk)
              #pragma unroll
              for (int m=0;m<2;++m) bad |= isS(a[kk][m]);
            if (bad) __builtin_amdgcn_s_sleep(1);
          } while (bad && ++gd < GUARD);
          __builtin_amdgcn_sched_barrier(0);
        } else {
          #pragma unroll
          for (int kk=0; kk<8; ++kk)
            #pragma unroll
            for (int m=0;m<2;++m) a[kk][m] = Z4;
        }
        #pragma unroll
        for (int kk=0; kk<8; ++kk)
          #pragma unroll
          for (int g=0;g<4;++g){
            short8 bf = BL[((w*8+kk)*4+g)*64 + l];
            acc[0][g] = __builtin_amdgcn_mfma_f32_16x16x32_bf16(__builtin_bit_cast(short8, a[kk][0]), bf, acc[0][g],0,0,0);
            acc[1][g] = __builtin_amdgcn_mfma_f32_16x16x32_bf16(__builtin_bit_cast(short8, a[kk][1]), bf, acc[1][g],0,0,0);
          }
      }

      // 2-round split-K reduce
      {
        float* P = (w&1) ? P1 : P0;
        if (w < 2){
          #pragma unroll
          for (int m=0;m<2;++m)
            #pragma unroll
            for (int g=0;g<4;++g)
              #pragma unroll
              for (int r=0;r<4;++r)
                P[(m*16 + (lg<<2) + r)*68 + g*16 + lr] = acc[m][g][r];
        }
        __syncthreads();
        if (w >= 2){
          #pragma unroll
          for (int m=0;m<2;++m)
            #pragma unroll
            for (int g=0;g<4;++g)
              #pragma unroll
              for (int r=0;r<4;++r)
                P[(m*16 + (lg<<2) + r)*68 + g*16 + lr] += acc[m][g][r];
        }
        __syncthreads();
      }

      // WAR check (cross flag) + sentinel-clears (issued after the flag wait)
      if (w == 0){
        drain_vm();
        __builtin_amdgcn_sched_barrier(0);
        if (gateAct && l < ng){
          const int n0 = isC0 ? (t-4) : (t-516);
          const int need = (n0 < 1) ? 1 : n0;
          int v = (int)fv, gd = 0;
          while (v < need && ++gd < GUARD){ v = (int)ld_f4(fp, false); __builtin_amdgcn_s_sleep(2); }
        }
        if (t >= 4 && t <= 1019){
          const int row = l>>1, half = l&1;
          const size_t off = ((size_t)slotC*64 + bt*32 + row)*512 + ub*16 + half*8;
          if (isC0){
            st_r16(OWN0 + off, S4, loc);
            if (loc) st_r16(B0e + off, S4, false);
          } else {
            if (loc){
              st_r16(A1e + off, S4, true);
              if (t+3 >= 512) st_r16(B1e + off, S4, false);
            } else {
              st_r16(((t+3 >= 512) ? B1e : A1e) + off, S4, false);
            }
          }
        }
      }

      // activation epilogue -> LDS staging
      const float* bias = (t<512) ? be : bd;
      #pragma unroll
      for (int s=0;s<2;++s){
        const int row = (tid>>4) + s*16;
        const int pi = row*68 + u;
        float gi = P0[pi]      + P1[pi]      + bias[0];
        float gf = P0[pi+16]   + P1[pi+16]   + bias[1];
        float gg = P0[pi+32]   + P1[pi+32]   + bias[2];
        float go = P0[pi+48]   + P1[pi+48]   + bias[3];
        float cprev = s ? cS1 : cS0;
        float c = sigm(gf)*cprev + sigm(gi)*tanh_(gg);
        if (s) cS1 = c; else cS0 = c;
        float h = sigm(go)*tanh_(c);
        HS[row*16 + u] = f2bf(h);
      }
      __syncthreads();
      // publish (dual when loc; single MALL ring when !loc, == r8)
      if (tid < 64){
        u32x4 v = *(const u32x4*)(HS + tid*8);
        const int row = tid>>1, half = tid&1;
        const size_t off = ((size_t)slotW*64 + bt*32 + row)*512 + ub*16 + half*8;
        if (isC0){
          st_r16(OWN0 + off, v, loc);
          if (loc) st_r16(B0e + off, v, false);
        } else {
          if (loc){
            st_r16(A1e + off, v, true);
            if (t >= 512) st_r16(B1e + off, v, false);
          } else {
            st_r16(((t >= 512) ? B1e : A1e) + off, v, false);
          }
        }
      }
      if (!isC0 && tid == 0)
        st_f4(ws + OFC1 + (size_t)(bt*32+ub)*64, (unsigned)(t+1), false);
    }
  } else if (role == 2){
    // ---------------- clf hidden: relu(h1 @ W1^T + b1) ----------------
    const int hwg = j;
    const int u = tid&15, col = hwg*16 + u;
    const float bc = cb1[col];
    loadB((size_t)OWC1 + (size_t)hwg*16384, 16384);
    __syncthreads();
    for (int t2 = 0; t2 < 511; ++t2){
      const int slot = t2&7, slotC = (t2+3)&7;
      const bool gateAct = (t2 >= 5);
      const void* fp = (const void*)(ws + OFL + (size_t)(l&7)*64);
      unsigned fv = 0u;
      if (w == 0 && l < 8 && gateAct) fv = ld_f4a(fp, loc);

      u32x4 a[4][4];
      const unsigned short* base = B1e + (size_t)slot*64*512;
      int gd = 0; bool bad;
      do {
        #pragma unroll
        for (int kk=0; kk<4; ++kk)
          #pragma unroll
          for (int m=0;m<4;++m)
            a[kk][m] = ld_r16(base + (size_t)(m*16+lr)*512 + w*128 + kk*32 + (lg<<3), false);
        drain_vm();
        __builtin_amdgcn_sched_barrier(0);   // rule #18
        bad = false;
        #pragma unroll
        for (int kk=0; kk<4; ++kk)
          #pragma unroll
          for (int m=0;m<4;++m) bad |= isS(a[kk][m]);
        if (bad) __builtin_amdgcn_s_sleep(1);
      } while (bad && ++gd < GUARD);
      __builtin_amdgcn_sched_barrier(0);
      f32x4 ha[4];
      #pragma unroll
      for (int m=0;m<4;++m) ha[m] = (f32x4){0.f,0.f,0.f,0.f};
      #pragma unroll
      for (int kk=0; kk<4; ++kk){
        short8 bf = BL[(w*4+kk)*64 + l];
        #pragma unroll
        for (int m=0;m<4;++m)
          ha[m] = __builtin_amdgcn_mfma_f32_16x16x32_bf16(__builtin_bit_cast(short8, a[kk][m]), bf, ha[m],0,0,0);
      }
      {
        float* P = (w&1) ? P1 : P0;
        if (w < 2){
          #pragma unroll
          for (int m=0;m<4;++m)
            #pragma unroll
            for (int r=0;r<4;++r)
              P[(m*16 + (lg<<2) + r)*20 + lr] = ha[m][r];
        }
        __syncthreads();
        if (w >= 2){
          #pragma unroll
          for (int m=0;m<4;++m)
            #pragma unroll
            for (int r=0;r<4;++r)
              P[(m*16 + (lg<<2) + r)*20 + lr] += ha[m][r];
        }
        __syncthreads();
      }
      if (w == 0){
        drain_vm();
        __builtin_amdgcn_sched_barrier(0);
        if (gateAct && l < 8){
          const int n0 = t2 - 4;
          const int need = (n0 < 1) ? 1 : n0;
          int v = (int)fv, g2 = 0;
          while (v < need && ++g2 < GUARD){ v = (int)ld_f4(fp, loc); __builtin_amdgcn_s_sleep(2); }
        }
        if (t2 >= 5 && t2 <= 507){
          #pragma unroll
          for (int q=0;q<2;++q)
            st_r16(hpr + ((size_t)slotC*64 + l)*256 + hwg*16 + q*8, S4, loc);
        }
      }
      #pragma unroll
      for (int s=0;s<4;++s){
        const int row = (tid>>4) + s*16;
        float v = P0[row*20+u] + P1[row*20+u] + bc;
        HS[row*16 + u] = f2bf(fmaxf(v, 0.f));
      }
      __syncthreads();
      if (tid < 128){
        u32x4 v = *(const u32x4*)(HS + tid*8);
        const int row = tid>>1, half = tid&1;
        st_r16(hpr + ((size_t)slot*64 + row)*256 + hwg*16 + half*8, v, loc);
      }
      if (tid == 0) st_f4(ws + OFH + (size_t)hwg*64, (unsigned)(t2+1), false);
    }
  } else {
    // ---------------- clf logits: hid @ W2^T + b2 -> out ----------------
    const int lwg = j - 16;
    const int u = tid&15, col = lwg*16 + u;
    const float bc = cb2[col];
    loadB((size_t)OWC2 + (size_t)lwg*8192, 8192);
    __syncthreads();
    for (int t3 = 0; t3 < 511; ++t3){
      const int slot = t3&7;
      u32x4 a[2][4];
      const unsigned short* base = hpr + (size_t)slot*64*256;
      int gd = 0; bool bad;
      do {
        #pragma unroll
        for (int kk=0; kk<2; ++kk)
          #pragma unroll
          for (int m=0;m<4;++m)
            a[kk][m] = ld_r16(base + (size_t)(m*16+lr)*256 + w*64 + kk*32 + (lg<<3), loc);
        drain_vm();
        __builtin_amdgcn_sched_barrier(0);   // rule #18
        bad = false;
        #pragma unroll
        for (int kk=0; kk<2; ++kk)
          #pragma unroll
          for (int m=0;m<4;++m) bad |= isS(a[kk][m]);
        if (bad) __builtin_amdgcn_s_sleep(1);
      } while (bad && ++gd < GUARD);
      __builtin_amdgcn_sched_barrier(0);
      f32x4 la[4];
      #pragma unroll
      for (int m=0;m<4;++m) la[m] = (f32x4){0.f,0.f,0.f,0.f};
      #pragma unroll
      for (int kk=0; kk<2; ++kk){
        short8 bf = BL[(w*2+kk)*64 + l];
        #pragma unroll
        for (int m=0;m<4;++m)
          la[m] = __builtin_amdgcn_mfma_f32_16x16x32_bf16(__builtin_bit_cast(short8, a[kk][m]), bf, la[m],0,0,0);
      }
      {
        float* P = (w&1) ? P1 : P0;
        if (w < 2){
          #pragma unroll
          for (int m=0;m<4;++m)
            #pragma unroll
            for (int r=0;r<4;++r)
              P[(m*16 + (lg<<2) + r)*20 + lr] = la[m][r];
        }
        __syncthreads();
        if (w >= 2){
          #pragma unroll
          for (int m=0;m<4;++m)
            #pragma unroll
            for (int r=0;r<4;++r)
              P[(m*16 + (lg<<2) + r)*20 + lr] += la[m][r];
        }
        __syncthreads();
      }
      #pragma unroll
      for (int s=0;s<4;++s){
        const int row = (tid>>4) + s*16;
        float v = P0[row*20+u] + P1[row*20+u] + bc;
        out[((size_t)row*512 + (t3+1))*128 + col] = v;
      }
      if (tid == 0) st_f4(ws + OFL + (size_t)lwg*64, (unsigned)(t3+1), loc);
    }
  }
}

// ---------------- launch ----------------
extern "C" void kernel_launch(void* const* d_in, const int* in_sizes, int n_in,
                              void* d_out, int out_size, void* d_ws, size_t ws_size,
                              hipStream_t stream){
  const float* x   = (const float*)d_in[0];
  const float* y   = (const float*)d_in[1];
  const float* eW0 = (const float*)d_in[2];
  const float* eU0 = (const float*)d_in[3];
  const float* eb0 = (const float*)d_in[4];
  const float* eW1 = (const float*)d_in[5];
  const float* eU1 = (const float*)d_in[6];
  const float* eb1 = (const float*)d_in[7];
  const float* dW0 = (const float*)d_in[8];
  const float* dU0 = (const float*)d_in[9];
  const float* db0 = (const float*)d_in[10];
  const float* dW1 = (const float*)d_in[11];
  const float* dU1 = (const float*)d_in[12];
  const float* db1 = (const float*)d_in[13];
  const float* cW1 = (const float*)d_in[14];
  const float* cb1 = (const float*)d_in[15];
  const float* cW2 = (const float*)d_in[16];
  const float* cb2 = (const float*)d_in[17];
  float* out = (float*)d_out;
  uint8_t* ws = (uint8_t*)d_ws;
  (void)in_sizes; (void)n_in; (void)out_size; (void)ws_size;

  k_init<<<dim3(256), dim3(256), 0, stream>>>(out, ws);
  k_cvt<<<dim3(2048), dim3(256), 0, stream>>>(x, y, ws);
  k_swzgate<<<dim3(1280), dim3(256), 0, stream>>>(eW0, eU0, ws, (size_t)OWE0, 128, 160, 5, 1);
  k_swzgate<<<dim3(1280), dim3(256), 0, stream>>>(dW0, dU0, ws, (size_t)OWD0, 128, 160, 5, 1);
  k_swzgate<<<dim3(2048), dim3(256), 0, stream>>>(eW1, eU1, ws, (size_t)OWE1, 512, 256, 8, 0);
  k_swzgate<<<dim3(2048), dim3(256), 0, stream>>>(dW1, dU1, ws, (size_t)OWD1, 512, 256, 8, 0);
  k_swzclf<<<dim3(256), dim3(256), 0, stream>>>(cW1, ws, (size_t)OWC1, 16, 128, 512);
  k_swzclf<<<dim3(64),  dim3(256), 0, stream>>>(cW2, ws, (size_t)OWC2, 8, 64, 256);
  k_seq<<<dim3(256), dim3(256), 0, stream>>>(ws, eb0, eb1, db0, db1, cb1, cb2, out);
}

// Round 11
// 5209.225 us; speedup vs baseline: 1.1094x; 1.0137x over previous
//
#include <hip/hip_runtime.h>
#include <hip/hip_bf16.h>
#include <stdint.h>

// B=64, T=512, D=128, H=512, C=256
#define SMEM_BYTES 150528

using short8  = __attribute__((ext_vector_type(8))) short;
using f32x4   = __attribute__((ext_vector_type(4))) float;
using u32x4   = __attribute__((ext_vector_type(4))) unsigned int;

// ---------------- workspace layout (bytes) ----------------
#define OXBF 0u
#define OYBF 8388608u
#define OWE0 16777216u               // cell0 enc blob: 32 ub * 81920
#define OWD0 (OWE0 + 2621440u)
#define OWE1 (OWD0 + 2621440u)       // cell1 enc blob: 32 ub * 131072
#define OWD1 (OWE1 + 4194304u)
#define OWC1 (OWD1 + 4194304u)       // 16 * 16KB
#define OWC2 (OWC1 + 262144u)        // 8 * 8KB
// rings: 32 slots deep (decoupling buffer)
#define OA0  (OWC2 + 65536u)         // h0 intra ring [32][64][512] bf16 = 2MB
#define OB0  (OA0 + 2097152u)        // h0 cross ring (MALL)
#define OA1  (OB0 + 2097152u)        // h1 intra ring
#define OB1  (OA1 + 2097152u)        // h1 cross ring (decoder contents only)
#define OHP  (OB1 + 2097152u)        // hid ring [32][64][256] = 1MB
#define OFLG (OHP + 1048576u)        // flags (64B apart)
#define OFC1 (OFLG + 4096u)          // c1 progress: 64 flags (MALL)
#define OFH  (OFLG + 8192u)          // hid progress: 16 flags (MALL)
#define OFL  (OFLG + 9216u)          // log progress: 8 flags
#define OPRB (OFLG + 16384u)         // probe tokens: 256 * 64B (sc0 world)
#define OVOT (OFLG + 32768u)         // probe votes:  256 * 64B (MALL world)

#define GUARD (1<<19)

// ---------------- helpers ----------------
static __device__ __forceinline__ unsigned short f2bf(float f){
  union { float f; unsigned u; } v; v.f = f;
  unsigned r = v.u + 0x7FFFu + ((v.u >> 16) & 1u);
  return (unsigned short)(r >> 16);
}
static __device__ __forceinline__ float sigm(float x){ return 1.f/(1.f+__expf(-x)); }
static __device__ __forceinline__ float tanh_(float x){ return 1.f - 2.f/(__expf(2.f*x)+1.f); }

// scoped access: loc=true -> sc0 (L2, same-XCD only); loc=false -> sc0 sc1 (MALL)
static __device__ __forceinline__ u32x4 ld_r16(const void* p, bool loc){
  u32x4 v;
  if (loc) asm volatile("global_load_dwordx4 %0, %1, off sc0"     : "=v"(v) : "v"(p) : "memory");
  else     asm volatile("global_load_dwordx4 %0, %1, off sc0 sc1" : "=v"(v) : "v"(p) : "memory");
  return v;
}
static __device__ __forceinline__ void st_r16(void* p, u32x4 v, bool loc){
  if (loc) asm volatile("global_store_dwordx4 %0, %1, off sc0"     :: "v"(p), "v"(v) : "memory");
  else     asm volatile("global_store_dwordx4 %0, %1, off sc0 sc1" :: "v"(p), "v"(v) : "memory");
}
static __device__ __forceinline__ unsigned ld_f4(const void* p, bool loc){
  unsigned v;
  if (loc) asm volatile("global_load_dword %0, %1, off sc0\n\ts_waitcnt vmcnt(0)"     : "=v"(v) : "v"(p) : "memory");
  else     asm volatile("global_load_dword %0, %1, off sc0 sc1\n\ts_waitcnt vmcnt(0)" : "=v"(v) : "v"(p) : "memory");
  return v;
}
static __device__ __forceinline__ void st_f4(void* p, unsigned v, bool loc){
  if (loc) asm volatile("global_store_dword %0, %1, off sc0"     :: "v"(p), "v"(v) : "memory");
  else     asm volatile("global_store_dword %0, %1, off sc0 sc1" :: "v"(p), "v"(v) : "memory");
}
static __device__ __forceinline__ unsigned ld_cg4(const void* p){ return ld_f4(p, false); }
static __device__ __forceinline__ void st_cg4(void* p, unsigned v){ st_f4(p, v, false); }
static __device__ __forceinline__ void drain_vm(){
  asm volatile("s_waitcnt vmcnt(0)" ::: "memory");
}
static __device__ __forceinline__ bool isS(u32x4 v){
  return (v[0]==0xFFFFFFFFu) | (v[1]==0xFFFFFFFFu) | (v[2]==0xFFFFFFFFu) | (v[3]==0xFFFFFFFFu);
}

// ---------------- prep kernels ----------------
__global__ void k_init(float* __restrict__ out, uint8_t* __restrict__ ws){
  int i = blockIdx.x*blockDim.x + threadIdx.x;
  int ns = gridDim.x*blockDim.x;
  uint32_t* r = (uint32_t*)(ws + OA0);
  const int nring = (4*2097152 + 1048576)/4;
  for (int k=i; k<nring; k+=ns) r[k] = 0xFFFFFFFFu;
  uint32_t* fl = (uint32_t*)(ws + OFLG);
  for (int k=i; k<49152/4; k+=ns) fl[k] = 0u;   // flags + probe + votes
  for (int k=i; k<64*128; k+=ns) out[(size_t)(k>>7)*(512*128) + (k&127)] = 0.f;
}

__global__ void k_cvt(const float* __restrict__ x, const float* __restrict__ y,
                      uint8_t* __restrict__ ws){
  unsigned short* xb = (unsigned short*)(ws + OXBF);
  unsigned short* yb = (unsigned short*)(ws + OYBF);
  const int n = 64*512*128;
  int i = blockIdx.x*blockDim.x + threadIdx.x, ns = gridDim.x*blockDim.x;
  for (int k=i; k<n; k+=ns){ xb[k] = f2bf(x[k]); yb[k] = f2bf(y[k]); }
}

__global__ void k_swzgate(const float* __restrict__ Wih, const float* __restrict__ Whh,
                          uint8_t* __restrict__ ws, size_t dstOff, int Kin, int KC, int NKK, int mode){
  unsigned short* dst = (unsigned short*)(ws + dstOff);
  const int total = 2048 * (KC*4);
  int i = blockIdx.x*blockDim.x + threadIdx.x, ns = gridDim.x*blockDim.x;
  for (int idx=i; idx<total; idx+=ns){
    int j = idx & 7;
    int lane = (idx >> 3) & 63;
    int t = idx >> 9;
    int g = t & 3; t >>= 2;
    int kk = t % NKK; t /= NKK;
    int w = t & 3; int ub = t >> 2;
    int off = ((lane>>4)<<3) + j;
    int k = mode ? (kk==0 ? w*32 + off : 128 + w*128 + (kk-1)*32 + off)
                 : (w*KC + kk*32 + off);
    int u = ub*16 + (lane&15);
    int row = g*512 + u;
    float v = (k < Kin) ? Wih[(size_t)row*Kin + k] : Whh[(size_t)row*512 + (k-Kin)];
    dst[idx] = f2bf(v);
  }
}

__global__ void k_swzclf(const float* __restrict__ W, uint8_t* __restrict__ ws,
                         size_t dstOff, int nwgs, int Kw, int Ktot){
  unsigned short* dst = (unsigned short*)(ws + dstOff);
  const int NKK = Kw/32;
  const int total = nwgs*4*NKK*64*8;
  int i = blockIdx.x*blockDim.x + threadIdx.x, ns = gridDim.x*blockDim.x;
  for (int idx=i; idx<total; idx+=ns){
    int j = idx & 7;
    int lane = (idx >> 3) & 63;
    int t = idx >> 9;
    int kk = t % NKK; t /= NKK;
    int w = t & 3; int wg = t >> 2;
    int k = w*Kw + kk*32 + ((lane>>4)<<3) + j;
    int col = wg*16 + (lane&15);
    dst[idx] = f2bf(W[(size_t)col*Ktot + k]);
  }
}

// ---------------- persistent dataflow kernel ----------------
// grid 256; xcd = wg&7, j = wg>>3:
//   xcd 0/1: cell0 bt=xcd (ub=j) | xcd 2/3: cell1 bt=xcd-2 | xcd 4: j<16 hid, j<24 log | else idle
__launch_bounds__(256, 1)
__global__ void k_seq(uint8_t* __restrict__ ws,
                      const float* __restrict__ eb0, const float* __restrict__ eb1,
                      const float* __restrict__ db0, const float* __restrict__ db1,
                      const float* __restrict__ cb1, const float* __restrict__ cb2,
                      float* __restrict__ out){
  __shared__ uint8_t smem[SMEM_BYTES];
  const int wg = blockIdx.x, tid = threadIdx.x;
  const int w = tid>>6, l = tid&63, lr = l&15, lg = l>>4;
  const int xcd = wg & 7, j = wg >> 3;

  int role; // 0=c0, 1=c1, 2=hid, 3=log
  if (xcd < 2) role = 0;
  else if (xcd < 4) role = 1;
  else if (xcd == 4 && j < 16) role = 2;
  else if (xcd == 4 && j < 24) role = 3;
  else return;

  const unsigned short* xb = (const unsigned short*)(ws+OXBF);
  const unsigned short* yb = (const unsigned short*)(ws+OYBF);
  unsigned short* A0e = (unsigned short*)(ws+OA0);
  unsigned short* B0e = (unsigned short*)(ws+OB0);
  unsigned short* A1e = (unsigned short*)(ws+OA1);
  unsigned short* B1e = (unsigned short*)(ws+OB1);
  unsigned short* hpr = (unsigned short*)(ws+OHP);

  short8* BL = (short8*)smem;
  float*  P0 = (float*)(smem + 131072);
  float*  P1 = (float*)(smem + 139776);
  unsigned short* HS = (unsigned short*)(smem + 148480);

  const u32x4 S4 = (u32x4){0xFFFFFFFFu,0xFFFFFFFFu,0xFFFFFFFFu,0xFFFFFFFFu};
  const u32x4 Z4 = (u32x4){0u,0u,0u,0u};

  // ---- empirical coherence probe: 3-gen bounded ping-pong over sc0 + MALL vote ----
  bool loc;
  {
    const int n   = (role <= 1) ? 32 : 24;
    const int bas = (role <= 1) ? xcd : 4;
    if (w == 0){
      bool ok = true;
      #pragma unroll 1
      for (int gen = 1; gen <= 3; ++gen){
        if (l == 0) st_f4(ws + OPRB + (size_t)wg*64u, (unsigned)gen, true);
        if (l < n){
          const void* p = ws + OPRB + (size_t)(bas + 8*l)*64u;
          int spins = 0; unsigned e;
          do { e = ld_f4(p, true); } while ((int)e < gen && ++spins < 1024);
          if ((int)e < gen) ok = false;
        }
      }
      unsigned long long b1 = __ballot(ok);
      bool wgok = (b1 == ~0ULL);
      if (l == 0) st_f4(ws + OVOT + (size_t)wg*64u, wgok ? 2u : 1u, false);
      bool vok = wgok;
      if (l < n){
        const void* p = ws + OVOT + (size_t)(bas + 8*l)*64u;
        unsigned v;
        do { v = ld_f4(p, false); } while (v == 0u);
        vok = vok && (v == 2u);
      }
      unsigned long long b2 = __ballot(vok);
      if (l == 0) *(int*)HS = (b2 == ~0ULL) ? 1 : 0;
    }
    __syncthreads();
    loc = (*(volatile int*)HS) != 0;
    __syncthreads();
  }

  auto loadB = [&](size_t srcOff, int bytes){
    const u32x4* s = (const u32x4*)(ws + srcOff);
    u32x4* d = (u32x4*)smem;
    for (int i = tid; i < bytes/16; i += 256) d[i] = s[i];
  };

  if (role <= 1){
    // ---------------- LSTM cells ----------------
    const bool isC0 = (role == 0);
    const int bt = isC0 ? xcd : xcd-2, ub = j;
    const int u = tid&15, ug = ub*16 + u;
    const int bbytes = isC0 ? 81920 : 131072;
    unsigned short* OWN0 = loc ? A0e : B0e;   // c0 own ring (scope loc)

    float be[4], bd[4];
    {
      const float* e = isC0 ? eb0 : eb1;
      const float* d = isC0 ? db0 : db1;
      #pragma unroll
      for (int g=0; g<4; ++g){ be[g] = e[g*512+ug]; bd[g] = d[g*512+ug]; }
    }
    loadB((isC0 ? (size_t)OWE0 : (size_t)OWE1) + (size_t)ub*bbytes, bbytes);
    float cS0 = 0.f, cS1 = 0.f;
    __syncthreads();

    for (int t = 0; t < 1023; ++t){
      if (t == 512){
        __syncthreads();
        loadB((isC0 ? (size_t)OWD0 : (size_t)OWD1) + (size_t)ub*bbytes, bbytes);
        __syncthreads();
      }

      const int slotW = t&31, slotR = (t+31)&31;

      f32x4 acc[2][4];
      #pragma unroll
      for (int m=0;m<2;++m)
        #pragma unroll
        for (int g=0;g<4;++g) acc[m][g] = (f32x4){0.f,0.f,0.f,0.f};

      if (isC0){
        const unsigned short* xs = (t<512) ? xb : yb;
        const int tt = (t<512) ? t : t-512;
        short8 ax[2];
        #pragma unroll
        for (int m=0;m<2;++m){
          const int b = bt*32 + m*16 + lr;
          ax[m] = *(const short8*)(xs + ((size_t)b*512 + tt)*128 + w*32 + (lg<<3));
        }
        u32x4 ah[4][2];
        if (t > 0){
          const unsigned short* base = OWN0 + (size_t)slotR*64*512;
          int gd = 0; bool bad;
          do {
            #pragma unroll
            for (int kk=0; kk<4; ++kk)
              #pragma unroll
              for (int m=0;m<2;++m){
                const int b = bt*32 + m*16 + lr;
                ah[kk][m] = ld_r16(base + (size_t)b*512 + w*128 + kk*32 + (lg<<3), loc);
              }
            drain_vm();
            __builtin_amdgcn_sched_barrier(0);   // rule #18
            bad = false;
            #pragma unroll
            for (int kk=0; kk<4; ++kk)
              #pragma unroll
              for (int m=0;m<2;++m) bad |= isS(ah[kk][m]);
            if (bad) __builtin_amdgcn_s_sleep(1);
          } while (bad && ++gd < GUARD);
          __builtin_amdgcn_sched_barrier(0);
        } else {
          #pragma unroll
          for (int kk=0; kk<4; ++kk)
            #pragma unroll
            for (int m=0;m<2;++m) ah[kk][m] = Z4;
        }
        #pragma unroll
        for (int g=0;g<4;++g){
          short8 bf = BL[((w*5+0)*4+g)*64 + l];
          acc[0][g] = __builtin_amdgcn_mfma_f32_16x16x32_bf16(ax[0], bf, acc[0][g],0,0,0);
          acc[1][g] = __builtin_amdgcn_mfma_f32_16x16x32_bf16(ax[1], bf, acc[1][g],0,0,0);
        }
        #pragma unroll
        for (int kk=1; kk<5; ++kk)
          #pragma unroll
          for (int g=0;g<4;++g){
            short8 bf = BL[((w*5+kk)*4+g)*64 + l];
            acc[0][g] = __builtin_amdgcn_mfma_f32_16x16x32_bf16(__builtin_bit_cast(short8, ah[kk-1][0]), bf, acc[0][g],0,0,0);
            acc[1][g] = __builtin_amdgcn_mfma_f32_16x16x32_bf16(__builtin_bit_cast(short8, ah[kk-1][1]), bf, acc[1][g],0,0,0);
          }
      } else {
        // waves 0-1: h0(t) from B0 (MALL); waves 2-3: h1(t-1) from own ring
        u32x4 a[8][2];
        const bool wv01 = (w < 2);
        if (wv01 || t > 0){
          const unsigned short* base;
          bool myloc;
          if (wv01){ base = B0e + (size_t)slotW*64*512; myloc = false; }
          else {
            base = (loc ? A1e : (((t-1) >= 512) ? B1e : A1e)) + (size_t)slotR*64*512;
            myloc = loc;
          }
          const int kbase = wv01 ? (w*256) : (w*256 - 512);
          int gd = 0; bool bad;
          do {
            #pragma unroll
            for (int kk=0; kk<8; ++kk)
              #pragma unroll
              for (int m=0;m<2;++m){
                const int b = bt*32 + m*16 + lr;
                a[kk][m] = ld_r16(base + (size_t)b*512 + kbase + kk*32 + (lg<<3), myloc);
              }
            drain_vm();
            __builtin_amdgcn_sched_barrier(0);   // rule #18
            bad = false;
            #pragma unroll
            for (int kk=0; kk<8; ++kk)
              #pragma unroll
              for (int m=0;m<2;++m) bad |= isS(a[kk][m]);
            if (bad) __builtin_amdgcn_s_sleep(1);
          } while (bad && ++gd < GUARD);
          __builtin_amdgcn_sched_barrier(0);
        } else {
          #pragma unroll
          for (int kk=0; kk<8; ++kk)
            #pragma unroll
            for (int m=0;m<2;++m) a[kk][m] = Z4;
        }
        #pragma unroll
        for (int kk=0; kk<8; ++kk)
          #pragma unroll
          for (int g=0;g<4;++g){
            short8 bf = BL[((w*8+kk)*4+g)*64 + l];
            acc[0][g] = __builtin_amdgcn_mfma_f32_16x16x32_bf16(__builtin_bit_cast(short8, a[kk][0]), bf, acc[0][g],0,0,0);
            acc[1][g] = __builtin_amdgcn_mfma_f32_16x16x32_bf16(__builtin_bit_cast(short8, a[kk][1]), bf, acc[1][g],0,0,0);
          }
      }

      // 2-round split-K reduce
      {
        float* P = (w&1) ? P1 : P0;
        if (w < 2){
          #pragma unroll
          for (int m=0;m<2;++m)
            #pragma unroll
            for (int g=0;g<4;++g)
              #pragma unroll
              for (int r=0;r<4;++r)
                P[(m*16 + (lg<<2) + r)*68 + g*16 + lr] = acc[m][g][r];
        }
        __syncthreads();
        if (w >= 2){
          #pragma unroll
          for (int m=0;m<2;++m)
            #pragma unroll
            for (int g=0;g<4;++g)
              #pragma unroll
              for (int r=0;r<4;++r)
                P[(m*16 + (lg<<2) + r)*68 + g*16 + lr] += acc[m][g][r];
        }
        __syncthreads();
      }

      // ---- amortized WAR gate + batched sentinel-clears (every 8 steps) ----
      if (w == 0 && (t & 7) == 0){
        drain_vm();
        __builtin_amdgcn_sched_barrier(0);
        if (isC0){
          if (t >= 24 && l < 32){
            const void* p = ws + OFC1 + (size_t)(bt*32+l)*64;
            const int need = (t-22 < 1) ? 1 : t-22;
            int v, gd = 0;
            do { v = (int)ld_f4(p, false); if (v < need) __builtin_amdgcn_s_sleep(2); }
            while (v < need && ++gd < GUARD);
          }
        } else {
          if (t >= 536 && l < 16){
            const void* p = ws + OFH + (size_t)l*64;
            const int need = (t-534 < 1) ? 1 : t-534;
            int v, gd = 0;
            do { v = (int)ld_f4(p, false); if (v < need) __builtin_amdgcn_s_sleep(2); }
            while (v < need && ++gd < GUARD);
          }
        }
        if (t >= 8){
          const int row = l>>1, half = l&1;
          #pragma unroll
          for (int a=2; a<=9; ++a){
            const int cs = (t+a)&31;
            const size_t off = ((size_t)cs*64 + bt*32 + row)*512 + ub*16 + half*8;
            if (isC0){
              st_r16(OWN0 + off, S4, loc);
              if (loc) st_r16(B0e + off, S4, false);
            } else {
              st_r16(loc ? A1e + off : (((t+a-32) >= 512) ? B1e + off : A1e + off), S4, loc ? true : false);
              if (loc && (t+a) >= 544) st_r16(B1e + off, S4, false);
            }
          }
        }
      }

      // activation epilogue -> LDS staging
      const float* bias = (t<512) ? be : bd;
      #pragma unroll
      for (int s=0;s<2;++s){
        const int row = (tid>>4) + s*16;
        const int pi = row*68 + u;
        float gi = P0[pi]      + P1[pi]      + bias[0];
        float gf = P0[pi+16]   + P1[pi+16]   + bias[1];
        float gg = P0[pi+32]   + P1[pi+32]   + bias[2];
        float go = P0[pi+48]   + P1[pi+48]   + bias[3];
        float cprev = s ? cS1 : cS0;
        float c = sigm(gf)*cprev + sigm(gi)*tanh_(gg);
        if (s) cS1 = c; else cS0 = c;
        float h = sigm(go)*tanh_(c);
        HS[row*16 + u] = f2bf(h);
      }
      __syncthreads();
      // publish (dual when loc; single MALL ring when !loc)
      if (tid < 64){
        u32x4 v = *(const u32x4*)(HS + tid*8);
        const int row = tid>>1, half = tid&1;
        const size_t off = ((size_t)slotW*64 + bt*32 + row)*512 + ub*16 + half*8;
        if (isC0){
          st_r16(OWN0 + off, v, loc);
          if (loc) st_r16(B0e + off, v, false);
        } else {
          if (loc){
            st_r16(A1e + off, v, true);
            if (t >= 512) st_r16(B1e + off, v, false);
          } else {
            st_r16(((t >= 512) ? B1e : A1e) + off, v, false);
          }
        }
      }
      if (!isC0 && tid == 0)
        st_f4(ws + OFC1 + (size_t)(bt*32+ub)*64, (unsigned)(t+1), false);
    }
  } else if (role == 2){
    // ---------------- clf hidden: relu(h1 @ W1^T + b1) ----------------
    const int hwg = j;
    const int u = tid&15, col = hwg*16 + u;
    const float bc = cb1[col];
    loadB((size_t)OWC1 + (size_t)hwg*16384, 16384);
    __syncthreads();
    for (int t2 = 0; t2 < 511; ++t2){
      const int slot = (512+t2)&31;

      u32x4 a[4][4];
      const unsigned short* base = B1e + (size_t)slot*64*512;
      int gd = 0; bool bad;
      do {
        #pragma unroll
        for (int kk=0; kk<4; ++kk)
          #pragma unroll
          for (int m=0;m<4;++m)
            a[kk][m] = ld_r16(base + (size_t)(m*16+lr)*512 + w*128 + kk*32 + (lg<<3), false);
        drain_vm();
        __builtin_amdgcn_sched_barrier(0);   // rule #18
        bad = false;
        #pragma unroll
        for (int kk=0; kk<4; ++kk)
          #pragma unroll
          for (int m=0;m<4;++m) bad |= isS(a[kk][m]);
        if (bad) __builtin_amdgcn_s_sleep(1);
      } while (bad && ++gd < GUARD);
      __builtin_amdgcn_sched_barrier(0);
      f32x4 ha[4];
      #pragma unroll
      for (int m=0;m<4;++m) ha[m] = (f32x4){0.f,0.f,0.f,0.f};
      #pragma unroll
      for (int kk=0; kk<4; ++kk){
        short8 bf = BL[(w*4+kk)*64 + l];
        #pragma unroll
        for (int m=0;m<4;++m)
          ha[m] = __builtin_amdgcn_mfma_f32_16x16x32_bf16(__builtin_bit_cast(short8, a[kk][m]), bf, ha[m],0,0,0);
      }
      {
        float* P = (w&1) ? P1 : P0;
        if (w < 2){
          #pragma unroll
          for (int m=0;m<4;++m)
            #pragma unroll
            for (int r=0;r<4;++r)
              P[(m*16 + (lg<<2) + r)*20 + lr] = ha[m][r];
        }
        __syncthreads();
        if (w >= 2){
          #pragma unroll
          for (int m=0;m<4;++m)
            #pragma unroll
            for (int r=0;r<4;++r)
              P[(m*16 + (lg<<2) + r)*20 + lr] += ha[m][r];
        }
        __syncthreads();
      }
      // amortized log-WAR gate + batched clears of hid ring
      if (w == 0 && (t2 & 7) == 0){
        drain_vm();
        __builtin_amdgcn_sched_barrier(0);
        if (t2 >= 24 && l < 8){
          const void* p = ws + OFL + (size_t)l*64;
          const int need = (t2-22 < 1) ? 1 : t2-22;
          int v, g2 = 0;
          do { v = (int)ld_f4(p, loc); if (v < need) __builtin_amdgcn_s_sleep(2); }
          while (v < need && ++g2 < GUARD);
        }
        if (t2 >= 8){
          #pragma unroll
          for (int a=2; a<=9; ++a){
            const int cs = (t2+a)&31;
            #pragma unroll
            for (int q=0;q<2;++q)
              st_r16(hpr + ((size_t)cs*64 + l)*256 + hwg*16 + q*8, S4, loc);
          }
        }
      }
      #pragma unroll
      for (int s=0;s<4;++s){
        const int row = (tid>>4) + s*16;
        float v = P0[row*20+u] + P1[row*20+u] + bc;
        HS[row*16 + u] = f2bf(fmaxf(v, 0.f));
      }
      __syncthreads();
      if (tid < 128){
        u32x4 v = *(const u32x4*)(HS + tid*8);
        const int row = tid>>1, half = tid&1;
        st_r16(hpr + ((size_t)(t2&31)*64 + row)*256 + hwg*16 + half*8, v, loc);
      }
      if (tid == 0) st_f4(ws + OFH + (size_t)hwg*64, (unsigned)(t2+1), false);
    }
  } else {
    // ---------------- clf logits: hid @ W2^T + b2 -> out ----------------
    const int lwg = j - 16;
    const int u = tid&15, col = lwg*16 + u;
    const float bc = cb2[col];
    loadB((size_t)OWC2 + (size_t)lwg*8192, 8192);
    __syncthreads();
    for (int t3 = 0; t3 < 511; ++t3){
      const int slot = t3&31;
      u32x4 a[2][4];
      const unsigned short* base = hpr + (size_t)slot*64*256;
      int gd = 0; bool bad;
      do {
        #pragma unroll
        for (int kk=0; kk<2; ++kk)
          #pragma unroll
          for (int m=0;m<4;++m)
            a[kk][m] = ld_r16(base + (size_t)(m*16+lr)*256 + w*64 + kk*32 + (lg<<3), loc);
        drain_vm();
        __builtin_amdgcn_sched_barrier(0);   // rule #18
        bad = false;
        #pragma unroll
        for (int kk=0; kk<2; ++kk)
          #pragma unroll
          for (int m=0;m<4;++m) bad |= isS(a[kk][m]);
        if (bad) __builtin_amdgcn_s_sleep(1);
      } while (bad && ++gd < GUARD);
      __builtin_amdgcn_sched_barrier(0);
      f32x4 la[4];
      #pragma unroll
      for (int m=0;m<4;++m) la[m] = (f32x4){0.f,0.f,0.f,0.f};
      #pragma unroll
      for (int kk=0; kk<2; ++kk){
        short8 bf = BL[(w*2+kk)*64 + l];
        #pragma unroll
        for (int m=0;m<4;++m)
          la[m] = __builtin_amdgcn_mfma_f32_16x16x32_bf16(__builtin_bit_cast(short8, a[kk][m]), bf, la[m],0,0,0);
      }
      {
        float* P = (w&1) ? P1 : P0;
        if (w < 2){
          #pragma unroll
          for (int m=0;m<4;++m)
            #pragma unroll
            for (int r=0;r<4;++r)
              P[(m*16 + (lg<<2) + r)*20 + lr] = la[m][r];
        }
        __syncthreads();
        if (w >= 2){
          #pragma unroll
          for (int m=0;m<4;++m)
            #pragma unroll
            for (int r=0;r<4;++r)
              P[(m*16 + (lg<<2) + r)*20 + lr] += la[m][r];
        }
        __syncthreads();
      }
      #pragma unroll
      for (int s=0;s<4;++s){
        const int row = (tid>>4) + s*16;
        float v = P0[row*20+u] + P1[row*20+u] + bc;
        out[((size_t)row*512 + (t3+1))*128 + col] = v;
      }
      if (tid == 0) st_f4(ws + OFL + (size_t)lwg*64, (unsigned)(t3+1), loc);
    }
  }
}

// ---------------- launch ----------------
extern "C" void kernel_launch(void* const* d_in, const int* in_sizes, int n_in,
                              void* d_out, int out_size, void* d_ws, size_t ws_size,
                              hipStream_t stream){
  const float* x   = (const float*)d_in[0];
  const float* y   = (const float*)d_in[1];
  const float* eW0 = (const float*)d_in[2];
  const float* eU0 = (const float*)d_in[3];
  const float* eb0 = (const float*)d_in[4];
  const float* eW1 = (const float*)d_in[5];
  const float* eU1 = (const float*)d_in[6];
  const float* eb1 = (const float*)d_in[7];
  const float* dW0 = (const float*)d_in[8];
  const float* dU0 = (const float*)d_in[9];
  const float* db0 = (const float*)d_in[10];
  const float* dW1 = (const float*)d_in[11];
  const float* dU1 = (const float*)d_in[12];
  const float* db1 = (const float*)d_in[13];
  const float* cW1 = (const float*)d_in[14];
  const float* cb1 = (const float*)d_in[15];
  const float* cW2 = (const float*)d_in[16];
  const float* cb2 = (const float*)d_in[17];
  float* out = (float*)d_out;
  uint8_t* ws = (uint8_t*)d_ws;
  (void)in_sizes; (void)n_in; (void)out_size; (void)ws_size;

  k_init<<<dim3(256), dim3(256), 0, stream>>>(out, ws);
  k_cvt<<<dim3(2048), dim3(256), 0, stream>>>(x, y, ws);
  k_swzgate<<<dim3(1280), dim3(256), 0, stream>>>(eW0, eU0, ws, (size_t)OWE0, 128, 160, 5, 1);
  k_swzgate<<<dim3(1280), dim3(256), 0, stream>>>(dW0, dU0, ws, (size_t)OWD0, 128, 160, 5, 1);
  k_swzgate<<<dim3(2048), dim3(256), 0, stream>>>(eW1, eU1, ws, (size_t)OWE1, 512, 256, 8, 0);
  k_swzgate<<<dim3(2048), dim3(256), 0, stream>>>(dW1, dU1, ws, (size_t)OWD1, 512, 256, 8, 0);
  k_swzclf<<<dim3(256), dim3(256), 0, stream>>>(cW1, ws, (size_t)OWC1, 16, 128, 512);
  k_swzclf<<<dim3(64),  dim3(256), 0, stream>>>(cW2, ws, (size_t)OWC2, 8, 64, 256);
  k_seq<<<dim3(256), dim3(256), 0, stream>>>(ws, eb0, eb1, db0, db1, cb1, cb2, out);
}